// Round 1
// baseline (2993.246 us; speedup 1.0000x reference)
//
#include <hip/hip_runtime.h>
#include <hip/hip_bf16.h>

// Sparse conv3x3x3 (C3->C64) + BN + ReLU + sparse conv3x3x3 (C64->C3).
// Layout decisions:
//  - one wave (64 lanes) == one voxel, lane d == hidden channel d
//    => nbr[k][n] is wave-uniform => the "if (j>=0) skip" branch has ZERO
//       divergence, and we do only ~4.7/27 of the dense gather work.
//  - h stored bf16 in d_ws (128 MB): halves intermediate traffic; error
//    ~sqrt(300)*2^-9*0.05 ~ 2e-3, well under the 0.11 threshold.
//  - BN folded into scale/shift applied during the conv2 gather (no extra
//    full pass over h).

#define KVOL 27
#define CHID 64

__global__ __launch_bounds__(256) void k_conv1(
    const float* __restrict__ feats,   // [N][3]
    const float* __restrict__ W1,      // [27][3][64]
    const int*   __restrict__ nbr,     // [27][N]
    __hip_bfloat16* __restrict__ hbuf, // [N][64] out
    float* __restrict__ gstats,        // [0:64]=sum [64:128]=sumsq (pre-zeroed)
    int N)
{
    const int d    = threadIdx.x & 63;
    const int wib  = threadIdx.x >> 6;
    const int wpb  = blockDim.x >> 6;
    float sum = 0.f, sumsq = 0.f;

    for (int n = blockIdx.x * wpb + wib; n < N; n += gridDim.x * wpb) {
        float acc = 0.f;
        for (int k = 0; k < KVOL; ++k) {
            const int j = nbr[k * N + n];           // wave-uniform
            if (j >= 0) {                            // uniform branch
                const float f0 = feats[3 * j + 0];
                const float f1 = feats[3 * j + 1];
                const float f2 = feats[3 * j + 2];
                const float* w = W1 + k * 192 + d;   // coalesced, L1-resident
                acc = fmaf(f0, w[0],   acc);
                acc = fmaf(f1, w[64],  acc);
                acc = fmaf(f2, w[128], acc);
            }
        }
        hbuf[(long long)n * CHID + d] = __float2bfloat16(acc);
        sum   += acc;
        sumsq += acc * acc;
    }

    // block reduce per channel (threads d, d+64, d+128, d+192)
    __shared__ float red[512];
    red[threadIdx.x]              = sum;
    red[blockDim.x + threadIdx.x] = sumsq;
    __syncthreads();
    if (threadIdx.x < 64) {
        float s = 0.f, q = 0.f;
        for (int t = threadIdx.x; t < blockDim.x; t += 64) {
            s += red[t];
            q += red[blockDim.x + t];
        }
        atomicAdd(&gstats[threadIdx.x],      s);
        atomicAdd(&gstats[64 + threadIdx.x], q);
    }
}

__global__ void k_bn(const float* __restrict__ gstats,
                     const float* __restrict__ gamma,
                     const float* __restrict__ beta,
                     float* __restrict__ sc_sh, float invN)
{
    const int d  = threadIdx.x;  // 64 threads
    const float mu  = gstats[d] * invN;
    const float var = gstats[64 + d] * invN - mu * mu;
    const float sc  = gamma[d] * rsqrtf(var + 1e-5f);
    sc_sh[d]      = sc;
    sc_sh[64 + d] = beta[d] - mu * sc;
}

__global__ __launch_bounds__(256) void k_conv2(
    const __hip_bfloat16* __restrict__ hbuf, // [N][64]
    const float* __restrict__ W2,            // [27][64][3]
    const int*   __restrict__ nbr,           // [27][N]
    const float* __restrict__ sc_sh,         // [0:64]=scale [64:128]=shift
    float* __restrict__ out,                 // [N][3]
    int N)
{
    const int d   = threadIdx.x & 63;
    const int wib = threadIdx.x >> 6;
    const int wpb = blockDim.x >> 6;
    const float sc = sc_sh[d];
    const float sh = sc_sh[64 + d];

    for (int n = blockIdx.x * wpb + wib; n < N; n += gridDim.x * wpb) {
        float a0 = 0.f, a1 = 0.f, a2 = 0.f;
        for (int k = 0; k < KVOL; ++k) {
            const int j = nbr[k * N + n];            // wave-uniform
            if (j >= 0) {
                float hb = __bfloat162float(hbuf[(long long)j * CHID + d]); // 128B coalesced
                hb = fmaxf(fmaf(hb, sc, sh), 0.f);   // BN + ReLU on the fly
                const float* w = W2 + (26 - k) * 192 + d * 3; // reversed kernel
                a0 = fmaf(hb, w[0], a0);
                a1 = fmaf(hb, w[1], a1);
                a2 = fmaf(hb, w[2], a2);
            }
        }
        // one 64-lane reduction per voxel
        for (int off = 32; off > 0; off >>= 1) {
            a0 += __shfl_down(a0, off);
            a1 += __shfl_down(a1, off);
            a2 += __shfl_down(a2, off);
        }
        if (d == 0) {
            out[(long long)n * 3 + 0] = a0;
            out[(long long)n * 3 + 1] = a1;
            out[(long long)n * 3 + 2] = a2;
        }
    }
}

extern "C" void kernel_launch(void* const* d_in, const int* in_sizes, int n_in,
                              void* d_out, int out_size, void* d_ws, size_t ws_size,
                              hipStream_t stream) {
    const float* feats = (const float*)d_in[0];
    const float* W1    = (const float*)d_in[1];
    const float* gamma = (const float*)d_in[2];
    const float* beta  = (const float*)d_in[3];
    const float* W2    = (const float*)d_in[4];
    const int*   nbr   = (const int*)  d_in[5];
    const int N = in_sizes[0] / 3;
    float* out = (float*)d_out;

    char* ws = (char*)d_ws;
    __hip_bfloat16* hbuf = (__hip_bfloat16*)ws;
    const size_t hbytes = (size_t)N * CHID * sizeof(__hip_bfloat16); // 128 MB
    float* gstats = (float*)(ws + hbytes);   // 128 floats
    float* sc_sh  = gstats + 128;            // 128 floats

    hipMemsetAsync(gstats, 0, 128 * sizeof(float), stream);

    k_conv1<<<4096, 256, 0, stream>>>(feats, W1, nbr, hbuf, gstats, N);
    k_bn<<<1, 64, 0, stream>>>(gstats, gamma, beta, sc_sh, 1.0f / (float)N);
    k_conv2<<<8192, 256, 0, stream>>>(hbuf, W2, nbr, sc_sh, out, N);
}

// Round 2
// 2481.903 us; speedup vs baseline: 1.2060x; 1.2060x over previous
//
#include <hip/hip_runtime.h>
#include <hip/hip_bf16.h>

// Sparse conv3x3x3 (C3->C64) + BN + ReLU + sparse conv3x3x3 (C64->C3).
//  - one wave == one voxel, lane d == hidden channel d  => nbr[k][n] is
//    wave-uniform => skip-invalid branch has zero divergence.
//  - readfirstlane(n) makes the index provably uniform -> nbr/feats loads
//    become scalar (SMEM) loads; branches become scalar branches.
//  - ALL gather loads for a voxel are issued as one independent burst
//    (invalid k clamped to row 0 -> L1-hot line), killing the 27x serial
//    latency chain that made R0 latency-bound (465 GB/s @ 18% VALU).
//  - W1/W2 staged in LDS (20.7 KB, <=2-way bank aliasing = free).
//  - h stored bf16 in d_ws (128 MB); BN folded into conv2's gather.

#define KVOL 27
#define CHID 64
#define NTH  256

__global__ __launch_bounds__(NTH) void k_conv1(
    const float* __restrict__ feats,   // [N][3]
    const float* __restrict__ W1,      // [27][3][64]
    const int*   __restrict__ nbr,     // [27][N]
    __hip_bfloat16* __restrict__ hbuf, // [N][64] out
    float* __restrict__ gstats,        // [0:64]=sum [64:128]=sumsq (zeroed)
    int N)
{
    __shared__ float lw[KVOL * 192];
    for (int i = threadIdx.x; i < KVOL * 192; i += NTH) lw[i] = W1[i];
    __syncthreads();

    const int d   = threadIdx.x & 63;
    const int wib = threadIdx.x >> 6;
    const int wpb = NTH >> 6;
    float sum = 0.f, sumsq = 0.f;

    for (int n0 = blockIdx.x * wpb + wib; n0 < N; n0 += gridDim.x * wpb) {
        const int n = __builtin_amdgcn_readfirstlane(n0);

        int j[KVOL];
        #pragma unroll
        for (int k = 0; k < KVOL; ++k) j[k] = nbr[k * N + n];  // uniform burst

        float acc = 0.f;
        #pragma unroll
        for (int kc = 0; kc < 3; ++kc) {       // chunks of 9: bounds regs
            float f0[9], f1[9], f2[9];
            #pragma unroll
            for (int t = 0; t < 9; ++t) {
                const int k  = kc * 9 + t;
                const int jc = j[k] < 0 ? 0 : j[k];   // clamp: L1-hot line
                f0[t] = feats[3 * jc + 0];
                f1[t] = feats[3 * jc + 1];
                f2[t] = feats[3 * jc + 2];
            }
            #pragma unroll
            for (int t = 0; t < 9; ++t) {
                const int k = kc * 9 + t;
                if (j[k] >= 0) {               // uniform (scalar) branch
                    const float* w = &lw[k * 192 + d];
                    acc = fmaf(f0[t], w[0],   acc);
                    acc = fmaf(f1[t], w[64],  acc);
                    acc = fmaf(f2[t], w[128], acc);
                }
            }
        }
        hbuf[(long long)n * CHID + d] = __float2bfloat16(acc);
        sum   += acc;
        sumsq += acc * acc;
    }

    __shared__ float red[2 * NTH];
    red[threadIdx.x]       = sum;
    red[NTH + threadIdx.x] = sumsq;
    __syncthreads();
    if (threadIdx.x < 64) {
        float s = 0.f, q = 0.f;
        for (int t = threadIdx.x; t < NTH; t += 64) {
            s += red[t];
            q += red[NTH + t];
        }
        atomicAdd(&gstats[threadIdx.x],      s);
        atomicAdd(&gstats[64 + threadIdx.x], q);
    }
}

__global__ void k_bn(const float* __restrict__ gstats,
                     const float* __restrict__ gamma,
                     const float* __restrict__ beta,
                     float* __restrict__ sc_sh, float invN)
{
    const int d  = threadIdx.x;  // 64 threads
    const float mu  = gstats[d] * invN;
    const float var = gstats[64 + d] * invN - mu * mu;
    const float sc  = gamma[d] * rsqrtf(var + 1e-5f);
    sc_sh[d]      = sc;
    sc_sh[64 + d] = beta[d] - mu * sc;
}

__global__ __launch_bounds__(NTH) void k_conv2(
    const __hip_bfloat16* __restrict__ hbuf, // [N][64]
    const float* __restrict__ W2,            // [27][64][3]
    const int*   __restrict__ nbr,           // [27][N]
    const float* __restrict__ sc_sh,         // [0:64]=scale [64:128]=shift
    float* __restrict__ out,                 // [N][3]
    int N)
{
    __shared__ float lw[KVOL * 192];
    for (int i = threadIdx.x; i < KVOL * 192; i += NTH) lw[i] = W2[i];
    __syncthreads();

    const int d   = threadIdx.x & 63;
    const int wib = threadIdx.x >> 6;
    const int wpb = NTH >> 6;
    const float sc = sc_sh[d];
    const float sh = sc_sh[64 + d];

    for (int n0 = blockIdx.x * wpb + wib; n0 < N; n0 += gridDim.x * wpb) {
        const int n = __builtin_amdgcn_readfirstlane(n0);

        int j[KVOL];
        #pragma unroll
        for (int k = 0; k < KVOL; ++k) j[k] = nbr[k * N + n];  // uniform burst

        float hv[KVOL];
        #pragma unroll
        for (int k = 0; k < KVOL; ++k) {       // dense burst, clamped
            const int jc = j[k] < 0 ? 0 : j[k];
            hv[k] = __bfloat162float(hbuf[(long long)jc * CHID + d]);
        }

        float a0 = 0.f, a1 = 0.f, a2 = 0.f;
        #pragma unroll
        for (int k = 0; k < KVOL; ++k) {
            if (j[k] >= 0) {                   // uniform (scalar) branch
                const float hb = fmaxf(fmaf(hv[k], sc, sh), 0.f);
                const float* w = &lw[(26 - k) * 192 + d * 3];
                a0 = fmaf(hb, w[0], a0);
                a1 = fmaf(hb, w[1], a1);
                a2 = fmaf(hb, w[2], a2);
            }
        }
        for (int off = 32; off > 0; off >>= 1) {
            a0 += __shfl_down(a0, off);
            a1 += __shfl_down(a1, off);
            a2 += __shfl_down(a2, off);
        }
        if (d == 0) {
            out[(long long)n * 3 + 0] = a0;
            out[(long long)n * 3 + 1] = a1;
            out[(long long)n * 3 + 2] = a2;
        }
    }
}

extern "C" void kernel_launch(void* const* d_in, const int* in_sizes, int n_in,
                              void* d_out, int out_size, void* d_ws, size_t ws_size,
                              hipStream_t stream) {
    const float* feats = (const float*)d_in[0];
    const float* W1    = (const float*)d_in[1];
    const float* gamma = (const float*)d_in[2];
    const float* beta  = (const float*)d_in[3];
    const float* W2    = (const float*)d_in[4];
    const int*   nbr   = (const int*)  d_in[5];
    const int N = in_sizes[0] / 3;
    float* out = (float*)d_out;

    char* ws = (char*)d_ws;
    __hip_bfloat16* hbuf = (__hip_bfloat16*)ws;
    const size_t hbytes = (size_t)N * CHID * sizeof(__hip_bfloat16); // 128 MB
    float* gstats = (float*)(ws + hbytes);   // 128 floats
    float* sc_sh  = gstats + 128;            // 128 floats

    hipMemsetAsync(gstats, 0, 128 * sizeof(float), stream);

    k_conv1<<<8192, NTH, 0, stream>>>(feats, W1, nbr, hbuf, gstats, N);
    k_bn<<<1, 64, 0, stream>>>(gstats, gamma, beta, sc_sh, 1.0f / (float)N);
    k_conv2<<<8192, NTH, 0, stream>>>(hbuf, W2, nbr, sc_sh, out, N);
}

// Round 3
// 1307.240 us; speedup vs baseline: 2.2897x; 1.8986x over previous
//
#include <hip/hip_runtime.h>
#include <hip/hip_bf16.h>

// Sparse conv3x3x3 (3->64) + BN + ReLU + sparse conv3x3x3 (64->3), N=1M.
// R2 restructure: lane = voxel (not channel).
//  - nbr loads become coalesced 256B vector loads (R0/R1 had 4B/wave scalar
//    payloads -> in-flight bytes starvation -> 430 GB/s latency wall).
//  - h stored TRANSPOSED h_t[64][Ns] bf16; gather h_t[d][j[lane]] for 64
//    consecutive voxels is near-contiguous (monotone n->j map, slope ~1).
//  - invalid neighbors redirect to zero pad column at index N: no mask math.
//  - conv1: f[81] per-lane VGPRs, d-sweep with W1^T rows as uniform s_loads,
//    coalesced 128B h_t row stores. BN stats = separate streaming pass.
//  - conv2: per (k,d): gather + BN/ReLU on the fly + 3 FMA w/ uniform W2.
//    Chunked XCD swizzle keeps the dx +-5000-row reuse window in per-XCD L2.

#define KVOL 27
#define CHID 64

__global__ __launch_bounds__(256) void k_prep(
    const float* __restrict__ feats, const float* __restrict__ W1,
    float* __restrict__ f_t, float* __restrict__ W1t,
    __hip_bfloat16* __restrict__ h_t, int N, int Ns)
{
    const int b = blockIdx.x;
    if (b == 0) {
        // W1t[d][k*3+c] = W1[k][c][d]  (W1 is [27][3][64])
        for (int i = threadIdx.x; i < 64 * 81; i += 256) {
            const int d = i / 81, kc = i % 81;
            W1t[i] = W1[kc * 64 + d];
        }
        for (int i = threadIdx.x; i < 3 * 64; i += 256) {   // f_t zero pad
            const int c = i / 64, p = i % 64;
            f_t[(long long)c * Ns + N + p] = 0.f;
        }
        for (int i = threadIdx.x; i < 64 * 64; i += 256) {  // h_t zero pad
            const int d = i / 64, p = i % 64;
            h_t[(long long)d * Ns + N + p] = __float2bfloat16(0.f);
        }
    } else {
        // feats[N][3] -> f_t[3][Ns] via LDS tile (stride-3 reads are
        // conflict-free: 3 coprime 32)
        __shared__ float tile[768];
        for (long long t0 = (long long)(b - 1) * 256; t0 < N;
             t0 += (long long)(gridDim.x - 1) * 256) {
            const int nrem = (int)min((long long)256, (long long)N - t0);
            __syncthreads();
            for (int i = threadIdx.x; i < 3 * nrem; i += 256)
                tile[i] = feats[t0 * 3 + i];
            __syncthreads();
            for (int i = threadIdx.x; i < nrem; i += 256) {
                f_t[0 * (long long)Ns + t0 + i] = tile[i * 3 + 0];
                f_t[1 * (long long)Ns + t0 + i] = tile[i * 3 + 1];
                f_t[2 * (long long)Ns + t0 + i] = tile[i * 3 + 2];
            }
        }
    }
}

__global__ __launch_bounds__(256) void k_conv1(
    const float* __restrict__ f_t, const float* __restrict__ W1t,
    const int* __restrict__ nbr, __hip_bfloat16* __restrict__ h_t,
    int N, int Ns)
{
    const int lane = threadIdx.x & 63;
    const int tile = (int)((blockIdx.x * 256u + threadIdx.x) >> 6);
    const long long n0 = (long long)tile * 64;
    if (n0 >= N) return;
    const int n = (int)(n0 + lane);

    int j[KVOL];
#pragma unroll
    for (int k = 0; k < KVOL; ++k) j[k] = nbr[(long long)k * N + n]; // coalesced burst
#pragma unroll
    for (int k = 0; k < KVOL; ++k) j[k] = (j[k] < 0) ? N : j[k];     // zero-row redirect

    float f[3 * KVOL];                       // per-lane gathered inputs
#pragma unroll
    for (int k = 0; k < KVOL; ++k) {
        f[3 * k + 0] = f_t[j[k]];
        f[3 * k + 1] = f_t[(long long)Ns + j[k]];
        f[3 * k + 2] = f_t[2 * (long long)Ns + j[k]];
    }

#pragma unroll 4
    for (int d = 0; d < CHID; ++d) {
        const float* __restrict__ w = W1t + d * 81;  // uniform -> s_loads
        float acc = 0.f;
#pragma unroll
        for (int kc = 0; kc < 81; ++kc) acc = fmaf(f[kc], w[kc], acc);
        h_t[(long long)d * Ns + n] = __float2bfloat16(acc);  // coalesced 128B
    }
}

__global__ __launch_bounds__(256) void k_stats(
    const __hip_bfloat16* __restrict__ h_t, float* __restrict__ gstats, int Ns)
{
    const int d = blockIdx.x;               // 64 channels
    const uint4* row = reinterpret_cast<const uint4*>(h_t + (long long)d * Ns);
    const int nvec = Ns / 8;                // pads are zero: harmless in sums
    float s = 0.f, q = 0.f;
    for (int i = blockIdx.y * 256 + threadIdx.x; i < nvec; i += gridDim.y * 256) {
        const uint4 u = row[i];
#define ACC2(wd) { float lo = __uint_as_float((wd) << 16); \
                   float hi = __uint_as_float((wd) & 0xFFFF0000u); \
                   s += lo + hi; q = fmaf(lo, lo, q); q = fmaf(hi, hi, q); }
        ACC2(u.x) ACC2(u.y) ACC2(u.z) ACC2(u.w)
#undef ACC2
    }
    __shared__ float r1[256], r2[256];
    r1[threadIdx.x] = s; r2[threadIdx.x] = q;
    __syncthreads();
    for (int off = 128; off > 0; off >>= 1) {
        if (threadIdx.x < off) {
            r1[threadIdx.x] += r1[threadIdx.x + off];
            r2[threadIdx.x] += r2[threadIdx.x + off];
        }
        __syncthreads();
    }
    if (threadIdx.x == 0) {
        atomicAdd(&gstats[d],      r1[0]);
        atomicAdd(&gstats[64 + d], r2[0]);
    }
}

__global__ void k_bn(const float* __restrict__ gstats,
                     const float* __restrict__ gamma,
                     const float* __restrict__ beta,
                     float* __restrict__ sc_sh, float invN)
{
    const int d = threadIdx.x;  // 64 threads
    const float mu  = gstats[d] * invN;
    const float var = gstats[64 + d] * invN - mu * mu;
    const float sc  = gamma[d] * rsqrtf(var + 1e-5f);
    sc_sh[d]      = sc;
    sc_sh[64 + d] = beta[d] - mu * sc;
}

__global__ __launch_bounds__(256) void k_conv2(
    const __hip_bfloat16* __restrict__ h_t, const float* __restrict__ W2,
    const int* __restrict__ nbr, const float* __restrict__ sc_sh,
    float* __restrict__ out, int N, int Ns, int nblk)
{
    // bijective chunked XCD swizzle: consecutive sb per XCD -> dx reuse
    // window (~2.3 MB) stays in that XCD's 4MB L2
    const int bid = blockIdx.x;
    const int q = nblk >> 3, r = nblk & 7;
    const int xcd = bid & 7, pos = bid >> 3;
    const int sb = (xcd < r) ? xcd * (q + 1) + pos
                             : r * (q + 1) + (xcd - r) * q + pos;
    const int lane = threadIdx.x & 63;
    const int tile = sb * 4 + (threadIdx.x >> 6);
    const long long n0 = (long long)tile * 64;
    if (n0 >= N) return;
    const int n = (int)(n0 + lane);

    float a0 = 0.f, a1 = 0.f, a2 = 0.f;
    int jn = nbr[n];                         // prefetch k=0
    for (int k = 0; k < KVOL; ++k) {
        const int j = (jn < 0) ? N : jn;     // zero-row redirect
        if (k + 1 < KVOL) jn = nbr[(long long)(k + 1) * N + n]; // hide under d-loop
        const __hip_bfloat16* hrow = h_t + j;
        const float* __restrict__ w = W2 + (26 - k) * 192;  // reversed kernel
#pragma unroll 8
        for (int d = 0; d < CHID; ++d) {
            const float hv = __bfloat162float(hrow[(long long)d * Ns]); // ~130B span
            const float x  = fmaxf(fmaf(hv, sc_sh[d], sc_sh[64 + d]), 0.f);
            a0 = fmaf(x, w[3 * d + 0], a0);
            a1 = fmaf(x, w[3 * d + 1], a1);
            a2 = fmaf(x, w[3 * d + 2], a2);
        }
    }
    out[3LL * n + 0] = a0;
    out[3LL * n + 1] = a1;
    out[3LL * n + 2] = a2;
}

extern "C" void kernel_launch(void* const* d_in, const int* in_sizes, int n_in,
                              void* d_out, int out_size, void* d_ws, size_t ws_size,
                              hipStream_t stream) {
    const float* feats = (const float*)d_in[0];
    const float* W1    = (const float*)d_in[1];
    const float* gamma = (const float*)d_in[2];
    const float* beta  = (const float*)d_in[3];
    const float* W2    = (const float*)d_in[4];
    const int*   nbr   = (const int*)  d_in[5];
    const int N  = in_sizes[0] / 3;
    const int Ns = N + 64;                   // zero pad column block
    float* out = (float*)d_out;

    char* ws = (char*)d_ws;
    __hip_bfloat16* h_t = (__hip_bfloat16*)ws;                 // 64*Ns*2 B
    size_t off = (size_t)64 * Ns * sizeof(__hip_bfloat16);
    float* f_t = (float*)(ws + off);                           // 3*Ns*4 B
    off += (size_t)3 * Ns * sizeof(float);
    float* W1t = (float*)(ws + off);                           // 5184*4 B
    off += (size_t)64 * 81 * sizeof(float);
    float* gstats = (float*)(ws + off);                        // 128 f32
    float* sc_sh  = gstats + 128;

    hipMemsetAsync(gstats, 0, 128 * sizeof(float), stream);

    const int ntiles = (N + 63) / 64;        // 15625
    const int nblk   = (ntiles + 3) / 4;     // 3907

    k_prep <<<257, 256, 0, stream>>>(feats, W1, f_t, W1t, h_t, N, Ns);
    k_conv1<<<nblk, 256, 0, stream>>>(f_t, W1t, nbr, h_t, N, Ns);
    k_stats<<<dim3(64, 30), 256, 0, stream>>>(h_t, gstats, Ns);
    k_bn   <<<1, 64, 0, stream>>>(gstats, gamma, beta, sc_sh, 1.0f / (float)N);
    k_conv2<<<nblk, 256, 0, stream>>>(h_t, W2, nbr, sc_sh, out, N, Ns, nblk);
}

// Round 5
// 582.415 us; speedup vs baseline: 5.1394x; 2.2445x over previous
//
#include <hip/hip_runtime.h>
#include <hip/hip_fp16.h>

// Sparse conv3x3x3 (3->64) + BN + ReLU + sparse conv3x3x3 (64->3), N=1M.
// R3: d-chunked fp16 h-layout + v_dot2_f32_f16 inner loop.
//  - h2[8][Ns][8] fp16: cell (dc,n) = 16B = channels dc*8..dc*8+7.
//    conv2 gather per (k,dc) = ONE dwordx4/lane, near-coalesced (monotone j)
//    -> 216 loads/lane vs R2's 1728 2B-gathers.
//  - BN+ReLU pre-applied in-place (streaming) so conv2 inner = pure dot2
//    with uniform (SGPR) packed-half2 W2: 96 dot2 per k per lane.
//  - conv1: lane=voxel, f[81] f32 gather from padded f_t columns, d-pair
//    sweep with uniform W1t s_loads, cvt_pkrtz + coalesced dword stores.
//  - invalid neighbors redirect to zeroed pad row N (no mask math).

#define KVOL 27
#define CHID 64

typedef _Float16 half2_t __attribute__((ext_vector_type(2)));
typedef unsigned int uint32;

static __device__ __forceinline__ float fdot2(uint32 u, uint32 w, float acc) {
    return __builtin_amdgcn_fdot2(__builtin_bit_cast(half2_t, u),
                                  __builtin_bit_cast(half2_t, w), acc, false);
}
static __device__ __forceinline__ uint32 pkh2(float a, float b) {  // RTZ pack
    auto p = __builtin_amdgcn_cvt_pkrtz(a, b);   // __fp16 ext_vector(2)
    return __builtin_bit_cast(uint32, p);
}
static __device__ __forceinline__ uint32 pk_rne(float a, float b) { // RNE pack
    _Float16 ha = (_Float16)a, hb = (_Float16)b;
    unsigned short ua = __builtin_bit_cast(unsigned short, ha);
    unsigned short ub = __builtin_bit_cast(unsigned short, hb);
    return (uint32)ua | ((uint32)ub << 16);
}
static __device__ __forceinline__ void unpk(uint32 u, float& lo, float& hi) {
    half2_t h = __builtin_bit_cast(half2_t, u);
    lo = (float)h.x; hi = (float)h.y;
}

__global__ __launch_bounds__(256) void k_prep(
    const float* __restrict__ feats, const float* __restrict__ W1,
    const float* __restrict__ W2,
    float* __restrict__ f_t, float* __restrict__ W1t, uint32* __restrict__ w2q,
    uint32* __restrict__ h2, int N, int Ns)
{
    const int b = blockIdx.x;
    if (b == 0) {
        // W1t[d][kc] = W1[kc][d]   (W1 is [27*3][64])
        for (int i = threadIdx.x; i < 64 * 81; i += 256) {
            const int d = i / 81, kc = i % 81;
            W1t[i] = W1[kc * 64 + d];
        }
        // w2q[k][dc][c][p] = half2( W2[26-k][8dc+2p][c], W2[26-k][8dc+2p+1][c] )
        for (int i = threadIdx.x; i < KVOL * 96; i += 256) {
            const int k = i / 96, r = i % 96;
            const int dc = r / 12, c = (r % 12) / 4, p = r & 3;
            const int d0 = dc * 8 + 2 * p;
            const float* src = W2 + (26 - k) * 192;
            w2q[i] = pk_rne(src[d0 * 3 + c], src[(d0 + 1) * 3 + c]);
        }
        for (int i = threadIdx.x; i < 3 * 64; i += 256) {     // f_t zero pad
            const int c = i >> 6, pp = i & 63;
            f_t[(long long)c * Ns + N + pp] = 0.f;
        }
        for (int i = threadIdx.x; i < 8 * 4; i += 256) {      // h2 zero pad row N
            const int dc = i >> 2, p = i & 3;
            h2[((long long)dc * Ns + N) * 4 + p] = 0u;
        }
    } else {
        // feats[N][3] -> f_t[3][Ns] via LDS tile
        __shared__ float tile[768];
        for (long long t0 = (long long)(b - 1) * 256; t0 < N;
             t0 += (long long)(gridDim.x - 1) * 256) {
            const int nrem = (int)min((long long)256, (long long)N - t0);
            __syncthreads();
            for (int i = threadIdx.x; i < 3 * nrem; i += 256)
                tile[i] = feats[t0 * 3 + i];
            __syncthreads();
            for (int i = threadIdx.x; i < nrem; i += 256) {
                f_t[0 * (long long)Ns + t0 + i] = tile[i * 3 + 0];
                f_t[1 * (long long)Ns + t0 + i] = tile[i * 3 + 1];
                f_t[2 * (long long)Ns + t0 + i] = tile[i * 3 + 2];
            }
        }
    }
}

__global__ __launch_bounds__(256) void k_conv1(
    const float* __restrict__ f_t, const float* __restrict__ W1t,
    const int* __restrict__ nbr, uint32* __restrict__ h2,
    int N, int Ns)
{
    const int lane = threadIdx.x & 63;
    const int tile = (int)((blockIdx.x * 256u + threadIdx.x) >> 6);
    const long long n0 = (long long)tile * 64;
    if (n0 >= N) return;
    const int n = (int)(n0 + lane);

    int j[KVOL];
#pragma unroll
    for (int k = 0; k < KVOL; ++k) j[k] = nbr[(long long)k * N + n]; // coalesced
#pragma unroll
    for (int k = 0; k < KVOL; ++k) j[k] = (j[k] < 0) ? N : j[k];     // zero-row

    float f[3 * KVOL];
#pragma unroll
    for (int k = 0; k < KVOL; ++k) {
        f[3 * k + 0] = f_t[j[k]];
        f[3 * k + 1] = f_t[Ns + j[k]];
        f[3 * k + 2] = f_t[2 * Ns + j[k]];
    }

#pragma unroll 2
    for (int t = 0; t < 32; ++t) {                 // d-pair sweep
        const float* __restrict__ w0 = W1t + (2 * t)     * 81;  // uniform s_load
        const float* __restrict__ w1 = W1t + (2 * t + 1) * 81;
        float a0 = 0.f, a1 = 0.f;
#pragma unroll
        for (int i = 0; i < 81; ++i) {
            a0 = fmaf(f[i], w0[i], a0);
            a1 = fmaf(f[i], w1[i], a1);
        }
        // cell (dc=t>>2, n), dword slot t&3; lanes consecutive n -> coalesced
        h2[((long long)(t >> 2) * Ns + n) * 4 + (t & 3)] = pkh2(a0, a1);
    }
}

__global__ __launch_bounds__(256) void k_stats(
    const uint32* __restrict__ h2, float* __restrict__ gstats, int N, int Ns)
{
    const int dc = blockIdx.y;
    const uint4* base = (const uint4*)(h2 + (long long)dc * Ns * 4);
    float s[8], q[8];
#pragma unroll
    for (int e = 0; e < 8; ++e) { s[e] = 0.f; q[e] = 0.f; }
    for (long long i = blockIdx.x * 256 + threadIdx.x; i < N;
         i += (long long)gridDim.x * 256) {
        const uint4 u = base[i];
        float lo, hi;
        unpk(u.x, lo, hi); s[0]+=lo; q[0]=fmaf(lo,lo,q[0]); s[1]+=hi; q[1]=fmaf(hi,hi,q[1]);
        unpk(u.y, lo, hi); s[2]+=lo; q[2]=fmaf(lo,lo,q[2]); s[3]+=hi; q[3]=fmaf(hi,hi,q[3]);
        unpk(u.z, lo, hi); s[4]+=lo; q[4]=fmaf(lo,lo,q[4]); s[5]+=hi; q[5]=fmaf(hi,hi,q[5]);
        unpk(u.w, lo, hi); s[6]+=lo; q[6]=fmaf(lo,lo,q[6]); s[7]+=hi; q[7]=fmaf(hi,hi,q[7]);
    }
#pragma unroll
    for (int e = 0; e < 8; ++e)
        for (int off = 32; off > 0; off >>= 1) {
            s[e] += __shfl_down(s[e], off);
            q[e] += __shfl_down(q[e], off);
        }
    __shared__ float red[4][16];
    const int wib = threadIdx.x >> 6, lane = threadIdx.x & 63;
    if (lane == 0) {
#pragma unroll
        for (int e = 0; e < 8; ++e) { red[wib][e] = s[e]; red[wib][8 + e] = q[e]; }
    }
    __syncthreads();
    if (threadIdx.x < 16) {
        const float v = red[0][threadIdx.x] + red[1][threadIdx.x]
                      + red[2][threadIdx.x] + red[3][threadIdx.x];
        const int e = threadIdx.x & 7;
        const int d = dc * 8 + e;
        atomicAdd(&gstats[threadIdx.x < 8 ? d : 64 + d], v);
    }
}

__global__ void k_bn(const float* __restrict__ gstats,
                     const float* __restrict__ gamma,
                     const float* __restrict__ beta,
                     float* __restrict__ sc_sh, float invN)
{
    const int d = threadIdx.x;  // 64 threads
    const float mu  = gstats[d] * invN;
    const float var = gstats[64 + d] * invN - mu * mu;
    const float sc  = gamma[d] * rsqrtf(var + 1e-5f);
    sc_sh[d]      = sc;
    sc_sh[64 + d] = beta[d] - mu * sc;
}

__global__ __launch_bounds__(256) void k_apply(
    uint32* __restrict__ h2, const float* __restrict__ sc_sh, int N, int Ns)
{
    const int dc = blockIdx.y;
    float sc[8], sh[8];
#pragma unroll
    for (int e = 0; e < 8; ++e) {
        sc[e] = sc_sh[dc * 8 + e];
        sh[e] = sc_sh[64 + dc * 8 + e];
    }
    uint4* base = (uint4*)(h2 + (long long)dc * Ns * 4);
    for (long long i = blockIdx.x * 256 + threadIdx.x; i < N;
         i += (long long)gridDim.x * 256) {
        uint4 u = base[i];
        float lo, hi; uint4 r;
        unpk(u.x, lo, hi);
        r.x = pkh2(fmaxf(fmaf(lo, sc[0], sh[0]), 0.f), fmaxf(fmaf(hi, sc[1], sh[1]), 0.f));
        unpk(u.y, lo, hi);
        r.y = pkh2(fmaxf(fmaf(lo, sc[2], sh[2]), 0.f), fmaxf(fmaf(hi, sc[3], sh[3]), 0.f));
        unpk(u.z, lo, hi);
        r.z = pkh2(fmaxf(fmaf(lo, sc[4], sh[4]), 0.f), fmaxf(fmaf(hi, sc[5], sh[5]), 0.f));
        unpk(u.w, lo, hi);
        r.w = pkh2(fmaxf(fmaf(lo, sc[6], sh[6]), 0.f), fmaxf(fmaf(hi, sc[7], sh[7]), 0.f));
        base[i] = r;
    }
}

__global__ __launch_bounds__(256) void k_conv2(
    const uint32* __restrict__ h2, const uint32* __restrict__ w2q,
    const int* __restrict__ nbr, float* __restrict__ out,
    int N, int Ns, int nblk)
{
    // bijective chunked XCD swizzle (dx reuse window stays in one XCD L2)
    const int bid = blockIdx.x;
    const int qq = nblk >> 3, rr = nblk & 7;
    const int xcd = bid & 7, pos = bid >> 3;
    const int sb = (xcd < rr) ? xcd * (qq + 1) + pos
                              : rr * (qq + 1) + (xcd - rr) * qq + pos;
    const int lane = threadIdx.x & 63;
    const int tile = sb * 4 + (threadIdx.x >> 6);
    const long long n0 = (long long)tile * 64;
    if (n0 >= N) return;
    const int n = (int)(n0 + lane);

    float a0 = 0.f, a1 = 0.f, a2 = 0.f;
    int jn = nbr[n];                                   // prefetch k=0
    for (int k = 0; k < KVOL; ++k) {
        const int j = (jn < 0) ? N : jn;               // zero-row redirect
        if (k + 1 < KVOL) jn = nbr[(long long)(k + 1) * N + n];

        uint4 u[8];
#pragma unroll
        for (int dc = 0; dc < 8; ++dc)                 // 8 x dwordx4, coalesced-ish
            u[dc] = *(const uint4*)(h2 + ((long long)dc * Ns + j) * 4);

        const uint32* __restrict__ w = w2q + k * 96;   // uniform -> s_load
#pragma unroll
        for (int dc = 0; dc < 8; ++dc) {
            const int wb = dc * 12;
            a0 = fdot2(u[dc].x, w[wb + 0], a0);
            a1 = fdot2(u[dc].x, w[wb + 4], a1);
            a2 = fdot2(u[dc].x, w[wb + 8], a2);
            a0 = fdot2(u[dc].y, w[wb + 1], a0);
            a1 = fdot2(u[dc].y, w[wb + 5], a1);
            a2 = fdot2(u[dc].y, w[wb + 9], a2);
            a0 = fdot2(u[dc].z, w[wb + 2], a0);
            a1 = fdot2(u[dc].z, w[wb + 6], a1);
            a2 = fdot2(u[dc].z, w[wb + 10], a2);
            a0 = fdot2(u[dc].w, w[wb + 3], a0);
            a1 = fdot2(u[dc].w, w[wb + 7], a1);
            a2 = fdot2(u[dc].w, w[wb + 11], a2);
        }
    }
    out[3LL * n + 0] = a0;
    out[3LL * n + 1] = a1;
    out[3LL * n + 2] = a2;
}

extern "C" void kernel_launch(void* const* d_in, const int* in_sizes, int n_in,
                              void* d_out, int out_size, void* d_ws, size_t ws_size,
                              hipStream_t stream) {
    const float* feats = (const float*)d_in[0];
    const float* W1    = (const float*)d_in[1];
    const float* gamma = (const float*)d_in[2];
    const float* beta  = (const float*)d_in[3];
    const float* W2    = (const float*)d_in[4];
    const int*   nbr   = (const int*)  d_in[5];
    const int N  = in_sizes[0] / 3;
    const int Ns = N + 64;
    float* out = (float*)d_out;

    char* ws = (char*)d_ws;
    uint32* h2 = (uint32*)ws;                                    // 8*Ns*16 B
    size_t off = (size_t)8 * Ns * 16;
    float* f_t = (float*)(ws + off);                             // 3*Ns*4 B
    off += (size_t)3 * Ns * sizeof(float);
    float* W1t = (float*)(ws + off);                             // 5184*4 B
    off += (size_t)64 * 81 * sizeof(float);
    uint32* w2q = (uint32*)(ws + off);                           // 2592*4 B
    off += (size_t)KVOL * 96 * sizeof(uint32);
    float* gstats = (float*)(ws + off);                          // 128 f32
    float* sc_sh  = gstats + 128;

    (void)hipMemsetAsync(gstats, 0, 128 * sizeof(float), stream);

    const int ntiles = (N + 63) / 64;
    const int nblk   = (ntiles + 3) / 4;

    k_prep <<<257, 256, 0, stream>>>(feats, W1, W2, f_t, W1t, w2q, h2, N, Ns);
    k_conv1<<<nblk, 256, 0, stream>>>(f_t, W1t, nbr, h2, N, Ns);
    k_stats<<<dim3(256, 8), 256, 0, stream>>>(h2, gstats, N, Ns);
    k_bn   <<<1, 64, 0, stream>>>(gstats, gamma, beta, sc_sh, 1.0f / (float)N);
    k_apply<<<dim3(256, 8), 256, 0, stream>>>(h2, sc_sh, N, Ns);
    k_conv2<<<nblk, 256, 0, stream>>>(h2, w2q, nbr, out, N, Ns, nblk);
}